// Round 5
// baseline (303.335 us; speedup 1.0000x reference)
//
#include <hip/hip_runtime.h>

#define CC 128
typedef unsigned short ushort_t;
typedef unsigned int uint_t;

__device__ __forceinline__ ushort_t f2bf(float f) {
    uint_t u = __float_as_uint(f);
    u = (u + 0x7FFFu + ((u >> 16) & 1u)) >> 16;   // RNE
    return (ushort_t)u;
}

// ---------------- Kernel 1: xw = x @ W  (fp32 math, bf16 store) ------------
// 64 rows x 128 cols per block (grid ~782), 2 rows x 16 cols per thread,
// W staged in double-buffered 16KB chunks (one barrier per chunk).
__global__ __launch_bounds__(256) void xw_kernel(const float* __restrict__ x,
                                                 const float* __restrict__ w,
                                                 ushort_t* __restrict__ xwb, int n) {
    __shared__ float ws[2][32 * CC];         // 2 x 16 KB
    const int tid = threadIdx.x;

    auto stage = [&](int chunk, int buf) {
        const float4* src = reinterpret_cast<const float4*>(&w[chunk * 32 * CC]);
        float4* dst = reinterpret_cast<float4*>(ws[buf]);
        #pragma unroll
        for (int i = 0; i < 4; ++i) dst[tid + i * 256] = src[tid + i * 256];
    };

    stage(0, 0);

    const int rowgrp = tid >> 3;             // 0..31
    const int cg = tid & 7;                  // colgroup 0..7
    const int row0 = blockIdx.x * 64 + rowgrp * 2;
    const int col0 = cg * 16;

    float acc[2][16] = {};
    for (int c = 0; c < 4; ++c) {
        __syncthreads();                     // chunk c staged
        if (c < 3) stage(c + 1, (c + 1) & 1);
        const float* wb = ws[c & 1];
        const int k0 = c * 32;
        for (int k = 0; k < 32; k += 4) {
            float4 xv0 = (row0 < n)
                ? *reinterpret_cast<const float4*>(&x[(size_t)row0 * CC + k0 + k])
                : make_float4(0.f, 0.f, 0.f, 0.f);
            float4 xv1 = (row0 + 1 < n)
                ? *reinterpret_cast<const float4*>(&x[(size_t)(row0 + 1) * CC + k0 + k])
                : make_float4(0.f, 0.f, 0.f, 0.f);
            #pragma unroll
            for (int kk = 0; kk < 4; ++kk) {
                float wv[16];
                #pragma unroll
                for (int c4 = 0; c4 < 4; ++c4)
                    *reinterpret_cast<float4*>(&wv[c4 * 4]) =
                        *reinterpret_cast<const float4*>(&wb[(k + kk) * CC + col0 + c4 * 4]);
                const float xs0 = (&xv0.x)[kk];
                const float xs1 = (&xv1.x)[kk];
                #pragma unroll
                for (int cc = 0; cc < 16; ++cc) {
                    acc[0][cc] += xs0 * wv[cc];
                    acc[1][cc] += xs1 * wv[cc];
                }
            }
        }
    }
    #pragma unroll
    for (int r = 0; r < 2; ++r) {
        if (row0 + r < n) {
            uint_t pk[8];
            #pragma unroll
            for (int c2 = 0; c2 < 8; ++c2)
                pk[c2] = (uint_t)f2bf(acc[r][c2 * 2]) | ((uint_t)f2bf(acc[r][c2 * 2 + 1]) << 16);
            ushort_t* o = &xwb[(size_t)(row0 + r) * CC + col0];
            *reinterpret_cast<uint4*>(o)     = *reinterpret_cast<uint4*>(pk);
            *reinterpret_cast<uint4*>(o + 8) = *reinterpret_cast<uint4*>(pk + 4);
        }
    }
}

// ---------------- Kernel 2: row & col histograms (int atomics) -------------
__global__ void hist_kernel(const int* __restrict__ ei, int* __restrict__ cnt_row,
                            int* __restrict__ cnt_col, int E) {
    int i = blockIdx.x * blockDim.x + threadIdx.x;
    int stride = gridDim.x * blockDim.x;
    for (; i < E; i += stride) {
        atomicAdd(&cnt_row[ei[i]], 1);
        atomicAdd(&cnt_col[ei[E + i]], 1);
    }
}

// ---------------- Kernel 3: blocksum + dinv + combo (fused) ----------------
__global__ void blocksum_kernel(const int* __restrict__ cnt_col, const int* __restrict__ cnt_row,
                                float* __restrict__ dinv, int* __restrict__ bsum,
                                const float* __restrict__ emb0, const float* __restrict__ emb1,
                                const float* __restrict__ emb2, float* __restrict__ combo, int n) {
    const int i = blockIdx.x * 256 + threadIdx.x;
    if (i < n) {
        int d = cnt_row[i];
        dinv[i] = (d > 0) ? rsqrtf((float)d) : 0.0f;
    }
    int v = (i < n) ? cnt_col[i] : 0;
    #pragma unroll
    for (int d = 32; d; d >>= 1) v += __shfl_down(v, d);
    __shared__ int wsum[4];
    if ((threadIdx.x & 63) == 0) wsum[threadIdx.x >> 6] = v;
    __syncthreads();
    if (threadIdx.x == 0) bsum[blockIdx.x] = wsum[0] + wsum[1] + wsum[2] + wsum[3];
    if (blockIdx.x < 60 && threadIdx.x < CC) {
        const int c = blockIdx.x, t = threadIdx.x;
        const int i0 = c / 12, j0 = (c % 12) / 2, k0 = c % 2;
        combo[c * CC + t] = emb0[i0 * CC + t] + emb1[j0 * CC + t] + emb2[k0 * CC + t];
    }
}

// ---------------- Kernels 4b/4c: scan of block sums, then offsets ----------
__global__ void bscan_kernel(const int* __restrict__ bsum, int* __restrict__ boff,
                             int nb, int* __restrict__ offs, int n) {
    __shared__ int tmp[256];
    const int t = threadIdx.x;
    int v = (t < nb) ? bsum[t] : 0;
    tmp[t] = v; __syncthreads();
    for (int d = 1; d < 256; d <<= 1) {
        int u = (t >= d) ? tmp[t - d] : 0; __syncthreads();
        tmp[t] += u; __syncthreads();
    }
    if (t < nb) boff[t] = tmp[t] - v;
    if (t == 255) offs[n] = tmp[255];
}

__global__ void offs_kernel(const int* __restrict__ cnt, const int* __restrict__ boff,
                            int* __restrict__ offs, int* __restrict__ next, int n) {
    __shared__ int tmp[256];
    const int t = threadIdx.x;
    const int i = blockIdx.x * 256 + t;
    int v = (i < n) ? cnt[i] : 0;
    tmp[t] = v; __syncthreads();
    for (int d = 1; d < 256; d <<= 1) {
        int u = (t >= d) ? tmp[t - d] : 0; __syncthreads();
        tmp[t] += u; __syncthreads();
    }
    if (i < n) {
        int e = boff[blockIdx.x] + tmp[t] - v;
        offs[i] = e;
        next[i] = e;
    }
}

// ---------------- Kernel 5: fill CSR records (row|code packed, dinv_row) ---
// relies on n <= 65536 so row fits in 16 bits (n = 50000 here).
__global__ void fill_kernel(const int* __restrict__ ei, const int* __restrict__ ef,
                            const float* __restrict__ dinv, int* __restrict__ next,
                            int2* __restrict__ sc, int E) {
    int i = blockIdx.x * blockDim.x + threadIdx.x;
    int stride = gridDim.x * blockDim.x;
    for (; i < E; i += stride) {
        int r = ei[i];
        int c = ei[E + i];
        int pos = atomicAdd(&next[c], 1);
        int code = ef[i * 3 + 0] * 12 + ef[i * 3 + 1] * 2 + ef[i * 3 + 2];
        sc[pos] = make_int2(r | (code << 16), __float_as_int(dinv[r]));
    }
}

// ---------------- Kernel 6: gather — 1 wave per node, 2 edges in flight ----
// lanes 0-31 take edges j, j+4, ...; lanes 32-63 take j+1+... (interleaved by
// half-wave); each lane covers 4 channels (uint2 of 4 bf16). Halves combined
// with shfl_xor(32) at the end.
__global__ void gather_kernel(const ushort_t* __restrict__ xwb, const int2* __restrict__ sc,
                              const int* __restrict__ offs, const float* __restrict__ dinv,
                              const float* __restrict__ combo, float* __restrict__ out, int n) {
    const int v = blockIdx.x * 4 + (threadIdx.x >> 6);
    if (v >= n) return;
    const int lane = threadIdx.x & 63;
    const int half = lane >> 5;         // which edge of the pair
    const int l32 = lane & 31;          // channel group: 4 floats
    const int end = offs[v + 1];

    float4 a0 = {0.f, 0.f, 0.f, 0.f}, a1 = {0.f, 0.f, 0.f, 0.f};

    #define GBODY(ACC, J)                                                                \
        {                                                                                \
            const int2 e_ = sc[J];                                                       \
            const int   r_ = e_.x & 0xFFFF, c_ = e_.x >> 16;                             \
            const float w_ = __int_as_float(e_.y);                                       \
            const uint2 u_ = *reinterpret_cast<const uint2*>(                            \
                &xwb[(size_t)r_ * CC + l32 * 4]);                                        \
            const float4 k_ = *reinterpret_cast<const float4*>(&combo[c_ * CC + l32 * 4]); \
            ACC.x += w_ * (__uint_as_float(u_.x << 16) + k_.x);                          \
            ACC.y += w_ * (__uint_as_float(u_.x & 0xFFFF0000u) + k_.y);                  \
            ACC.z += w_ * (__uint_as_float(u_.y << 16) + k_.z);                          \
            ACC.w += w_ * (__uint_as_float(u_.y & 0xFFFF0000u) + k_.w);                  \
        }

    int jj = offs[v] + half;
    for (; jj + 2 < end; jj += 4) { GBODY(a0, jj) GBODY(a1, jj + 2) }
    if (jj < end) GBODY(a0, jj)
    #undef GBODY

    a0.x += a1.x; a0.y += a1.y; a0.z += a1.z; a0.w += a1.w;
    a0.x += __shfl_xor(a0.x, 32);
    a0.y += __shfl_xor(a0.y, 32);
    a0.z += __shfl_xor(a0.z, 32);
    a0.w += __shfl_xor(a0.w, 32);

    if (half == 0) {
        const float s = dinv[v];
        *reinterpret_cast<float4*>(&out[(size_t)v * CC + l32 * 4]) =
            make_float4(s * a0.x, s * a0.y, s * a0.z, s * a0.w);
    }
}

extern "C" void kernel_launch(void* const* d_in, const int* in_sizes, int n_in,
                              void* d_out, int out_size, void* d_ws, size_t ws_size,
                              hipStream_t stream) {
    const float* x      = (const float*)d_in[0];
    const int*   ei     = (const int*)d_in[1];
    const int*   ef     = (const int*)d_in[2];
    const float* weight = (const float*)d_in[3];
    const float* emb0   = (const float*)d_in[4];
    const float* emb1   = (const float*)d_in[5];
    const float* emb2   = (const float*)d_in[6];
    float* out = (float*)d_out;

    const int n = in_sizes[0] / CC;        // 50000
    const int E = in_sizes[1] / 2;         // 625000
    const int nb = (n + 255) / 256;        // 196

    char* p = (char*)d_ws;
    auto alloc = [&](size_t bytes) {
        char* r = p;
        p += (bytes + 15) & ~(size_t)15;
        return r;
    };
    ushort_t* xwb   = (ushort_t*)alloc((size_t)n * CC * sizeof(ushort_t));
    float* combo    = (float*)alloc(60 * CC * sizeof(float));
    float* dinv     = (float*)alloc(n * sizeof(float));
    int*   cnt_row  = (int*)alloc(n * sizeof(int));
    int*   cnt_col  = (int*)alloc(n * sizeof(int));
    int*   offs     = (int*)alloc((n + 1) * sizeof(int));
    int*   next     = (int*)alloc(n * sizeof(int));
    int*   bsum     = (int*)alloc(nb * sizeof(int));
    int*   boff     = (int*)alloc(nb * sizeof(int));
    int2*  sc       = (int2*)alloc((size_t)E * sizeof(int2));

    hipMemsetAsync(cnt_row, 0, n * sizeof(int), stream);
    hipMemsetAsync(cnt_col, 0, n * sizeof(int), stream);

    // 1) xw = x @ W (bf16 output)
    xw_kernel<<<(n + 63) / 64, 256, 0, stream>>>(x, weight, xwb, n);
    // 2) histograms
    hist_kernel<<<2048, 256, 0, stream>>>(ei, cnt_row, cnt_col, E);
    // 3) blocksum + dinv + combo
    blocksum_kernel<<<nb, 256, 0, stream>>>(cnt_col, cnt_row, dinv, bsum,
                                            emb0, emb1, emb2, combo, n);
    // 4) scan
    bscan_kernel<<<1, 256, 0, stream>>>(bsum, boff, nb, offs, n);
    offs_kernel<<<nb, 256, 0, stream>>>(cnt_col, boff, offs, next, n);
    // 5) fill CSR records
    fill_kernel<<<2048, 256, 0, stream>>>(ei, ef, dinv, next, sc, E);
    // 6) gather
    gather_kernel<<<(n + 3) / 4, 256, 0, stream>>>(xwb, sc, offs, dinv, combo, out, n);
}

// Round 6
// 163.308 us; speedup vs baseline: 1.8574x; 1.8574x over previous
//
#include <hip/hip_runtime.h>

#define CC 128
typedef unsigned short ushort_t;
typedef unsigned int uint_t;
typedef __attribute__((ext_vector_type(8))) short short8_t;
typedef __attribute__((ext_vector_type(4))) float float4_t;

__device__ __forceinline__ ushort_t f2bf(float f) {
    uint_t u = __float_as_uint(f);
    u = (u + 0x7FFFu + ((u >> 16) & 1u)) >> 16;   // RNE
    return (ushort_t)u;
}

// ---------------- Kernel 0: pack W -> WbT[n][k] (bf16, transposed) ---------
__global__ void packw_kernel(const float* __restrict__ w, ushort_t* __restrict__ wbt) {
    const int i = blockIdx.x * 256 + threadIdx.x;     // 64 blocks x 256 = 16384
    if (i < CC * CC) {
        const int n = i >> 7, k = i & 127;
        wbt[i] = f2bf(w[k * CC + n]);
    }
}

// ---------------- Kernel 1: xw = x @ W via MFMA (split-precision A) --------
// 64 rows/block, 4 waves x 16 rows; each wave: 8 N-tiles of 16 cols, K=4x32.
// A: x loaded fp32, split into bf16 hi+lo -> W-rounding is the only new error.
// B: contiguous dwordx4 from WbT (L2-hot). No LDS, no barriers.
__global__ __launch_bounds__(256) void xw_kernel(const float* __restrict__ x,
                                                 const ushort_t* __restrict__ wbt,
                                                 ushort_t* __restrict__ xwb, int n) {
    const int wave = threadIdx.x >> 6;
    const int lane = threadIdx.x & 63;
    const int row0 = blockIdx.x * 64 + wave * 16;
    const int r  = lane & 15;        // A-row within tile / C-col
    const int kb = lane >> 4;        // k-block 0..3 (8 contiguous k each)
    const int arow = row0 + r;
    const bool rok = arow < n;

    float4_t acc[8];
    #pragma unroll
    for (int t = 0; t < 8; ++t) acc[t] = (float4_t){0.f, 0.f, 0.f, 0.f};

    #pragma unroll
    for (int ks = 0; ks < 4; ++ks) {
        short8_t ahi, alo;
        if (rok) {
            const float* xp = &x[(size_t)arow * CC + ks * 32 + kb * 8];
            const float4 x0 = *reinterpret_cast<const float4*>(xp);
            const float4 x1 = *reinterpret_cast<const float4*>(xp + 4);
            const float xv[8] = {x0.x, x0.y, x0.z, x0.w, x1.x, x1.y, x1.z, x1.w};
            #pragma unroll
            for (int i = 0; i < 8; ++i) {
                const ushort_t h = f2bf(xv[i]);
                ahi[i] = (short)h;
                const float hf = __uint_as_float((uint_t)h << 16);
                alo[i] = (short)f2bf(xv[i] - hf);
            }
        } else {
            #pragma unroll
            for (int i = 0; i < 8; ++i) { ahi[i] = 0; alo[i] = 0; }
        }
        #pragma unroll
        for (int nt = 0; nt < 8; ++nt) {
            // B-frag: lane holds B[kb*8 + i][nt*16 + r] = WbT[nt*16+r][ks*32+kb*8+i]
            const short8_t b = *reinterpret_cast<const short8_t*>(
                &wbt[(size_t)(nt * 16 + r) * CC + ks * 32 + kb * 8]);
            acc[nt] = __builtin_amdgcn_mfma_f32_16x16x32_bf16(alo, b, acc[nt], 0, 0, 0);
            acc[nt] = __builtin_amdgcn_mfma_f32_16x16x32_bf16(ahi, b, acc[nt], 0, 0, 0);
        }
    }
    // C/D layout (m89-verified): col = lane&15, row = (lane>>4)*4 + reg
    #pragma unroll
    for (int reg = 0; reg < 4; ++reg) {
        const int orow = row0 + kb * 4 + reg;
        if (orow < n) {
            #pragma unroll
            for (int nt = 0; nt < 8; ++nt)
                xwb[(size_t)orow * CC + nt * 16 + r] = f2bf(acc[nt][reg]);
        }
    }
}

// ---------------- Kernel 2: row & col histograms (int atomics) -------------
__global__ void hist_kernel(const int* __restrict__ ei, int* __restrict__ cnt_row,
                            int* __restrict__ cnt_col, int E) {
    int i = blockIdx.x * blockDim.x + threadIdx.x;
    int stride = gridDim.x * blockDim.x;
    for (; i < E; i += stride) {
        atomicAdd(&cnt_row[ei[i]], 1);
        atomicAdd(&cnt_col[ei[E + i]], 1);
    }
}

// ---------------- Kernel 3: blocksum + dinv + combo (fused) ----------------
__global__ void blocksum_kernel(const int* __restrict__ cnt_col, const int* __restrict__ cnt_row,
                                float* __restrict__ dinv, int* __restrict__ bsum,
                                const float* __restrict__ emb0, const float* __restrict__ emb1,
                                const float* __restrict__ emb2, float* __restrict__ combo, int n) {
    const int i = blockIdx.x * 256 + threadIdx.x;
    if (i < n) {
        int d = cnt_row[i];
        dinv[i] = (d > 0) ? rsqrtf((float)d) : 0.0f;
    }
    int v = (i < n) ? cnt_col[i] : 0;
    #pragma unroll
    for (int d = 32; d; d >>= 1) v += __shfl_down(v, d);
    __shared__ int wsum[4];
    if ((threadIdx.x & 63) == 0) wsum[threadIdx.x >> 6] = v;
    __syncthreads();
    if (threadIdx.x == 0) bsum[blockIdx.x] = wsum[0] + wsum[1] + wsum[2] + wsum[3];
    if (blockIdx.x < 60 && threadIdx.x < CC) {
        const int c = blockIdx.x, t = threadIdx.x;
        const int i0 = c / 12, j0 = (c % 12) / 2, k0 = c % 2;
        combo[c * CC + t] = emb0[i0 * CC + t] + emb1[j0 * CC + t] + emb2[k0 * CC + t];
    }
}

// ---------------- Kernels 4b/4c: scan of block sums, then offsets ----------
__global__ void bscan_kernel(const int* __restrict__ bsum, int* __restrict__ boff,
                             int nb, int* __restrict__ offs, int n) {
    __shared__ int tmp[256];
    const int t = threadIdx.x;
    int v = (t < nb) ? bsum[t] : 0;
    tmp[t] = v; __syncthreads();
    for (int d = 1; d < 256; d <<= 1) {
        int u = (t >= d) ? tmp[t - d] : 0; __syncthreads();
        tmp[t] += u; __syncthreads();
    }
    if (t < nb) boff[t] = tmp[t] - v;
    if (t == 255) offs[n] = tmp[255];
}

__global__ void offs_kernel(const int* __restrict__ cnt, const int* __restrict__ boff,
                            int* __restrict__ offs, int* __restrict__ next, int n) {
    __shared__ int tmp[256];
    const int t = threadIdx.x;
    const int i = blockIdx.x * 256 + t;
    int v = (i < n) ? cnt[i] : 0;
    tmp[t] = v; __syncthreads();
    for (int d = 1; d < 256; d <<= 1) {
        int u = (t >= d) ? tmp[t - d] : 0; __syncthreads();
        tmp[t] += u; __syncthreads();
    }
    if (i < n) {
        int e = boff[blockIdx.x] + tmp[t] - v;
        offs[i] = e;
        next[i] = e;
    }
}

// ---------------- Kernel 5: fill CSR records (row|code packed, dinv_row) ---
// relies on n <= 65536 so row fits in 16 bits (n = 50000 here).
__global__ void fill_kernel(const int* __restrict__ ei, const int* __restrict__ ef,
                            const float* __restrict__ dinv, int* __restrict__ next,
                            int2* __restrict__ sc, int E) {
    int i = blockIdx.x * blockDim.x + threadIdx.x;
    int stride = gridDim.x * blockDim.x;
    for (; i < E; i += stride) {
        int r = ei[i];
        int c = ei[E + i];
        int pos = atomicAdd(&next[c], 1);
        int code = ef[i * 3 + 0] * 12 + ef[i * 3 + 1] * 2 + ef[i * 3 + 2];
        sc[pos] = make_int2(r | (code << 16), __float_as_int(dinv[r]));
    }
}

// ---------------- Kernel 6: gather — 1 wave per node, 2 edges in flight ----
__global__ void gather_kernel(const ushort_t* __restrict__ xwb, const int2* __restrict__ sc,
                              const int* __restrict__ offs, const float* __restrict__ dinv,
                              const float* __restrict__ combo, float* __restrict__ out, int n) {
    const int v = blockIdx.x * 4 + (threadIdx.x >> 6);
    if (v >= n) return;
    const int lane = threadIdx.x & 63;
    const int half = lane >> 5;         // which edge of the pair
    const int l32 = lane & 31;          // channel group: 4 floats
    const int end = offs[v + 1];

    float4 a0 = {0.f, 0.f, 0.f, 0.f}, a1 = {0.f, 0.f, 0.f, 0.f};

    #define GBODY(ACC, J)                                                                \
        {                                                                                \
            const int2 e_ = sc[J];                                                       \
            const int   r_ = e_.x & 0xFFFF, c_ = e_.x >> 16;                             \
            const float w_ = __int_as_float(e_.y);                                       \
            const uint2 u_ = *reinterpret_cast<const uint2*>(                            \
                &xwb[(size_t)r_ * CC + l32 * 4]);                                        \
            const float4 k_ = *reinterpret_cast<const float4*>(&combo[c_ * CC + l32 * 4]); \
            ACC.x += w_ * (__uint_as_float(u_.x << 16) + k_.x);                          \
            ACC.y += w_ * (__uint_as_float(u_.x & 0xFFFF0000u) + k_.y);                  \
            ACC.z += w_ * (__uint_as_float(u_.y << 16) + k_.z);                          \
            ACC.w += w_ * (__uint_as_float(u_.y & 0xFFFF0000u) + k_.w);                  \
        }

    int jj = offs[v] + half;
    for (; jj + 2 < end; jj += 4) { GBODY(a0, jj) GBODY(a1, jj + 2) }
    if (jj < end) GBODY(a0, jj)
    #undef GBODY

    a0.x += a1.x; a0.y += a1.y; a0.z += a1.z; a0.w += a1.w;
    a0.x += __shfl_xor(a0.x, 32);
    a0.y += __shfl_xor(a0.y, 32);
    a0.z += __shfl_xor(a0.z, 32);
    a0.w += __shfl_xor(a0.w, 32);

    if (half == 0) {
        const float s = dinv[v];
        *reinterpret_cast<float4*>(&out[(size_t)v * CC + l32 * 4]) =
            make_float4(s * a0.x, s * a0.y, s * a0.z, s * a0.w);
    }
}

extern "C" void kernel_launch(void* const* d_in, const int* in_sizes, int n_in,
                              void* d_out, int out_size, void* d_ws, size_t ws_size,
                              hipStream_t stream) {
    const float* x      = (const float*)d_in[0];
    const int*   ei     = (const int*)d_in[1];
    const int*   ef     = (const int*)d_in[2];
    const float* weight = (const float*)d_in[3];
    const float* emb0   = (const float*)d_in[4];
    const float* emb1   = (const float*)d_in[5];
    const float* emb2   = (const float*)d_in[6];
    float* out = (float*)d_out;

    const int n = in_sizes[0] / CC;        // 50000
    const int E = in_sizes[1] / 2;         // 625000
    const int nb = (n + 255) / 256;        // 196

    char* p = (char*)d_ws;
    auto alloc = [&](size_t bytes) {
        char* r = p;
        p += (bytes + 15) & ~(size_t)15;
        return r;
    };
    ushort_t* xwb   = (ushort_t*)alloc((size_t)n * CC * sizeof(ushort_t));
    ushort_t* wbt   = (ushort_t*)alloc(CC * CC * sizeof(ushort_t));
    float* combo    = (float*)alloc(60 * CC * sizeof(float));
    float* dinv     = (float*)alloc(n * sizeof(float));
    int*   cnt_row  = (int*)alloc(n * sizeof(int));
    int*   cnt_col  = (int*)alloc(n * sizeof(int));
    int*   offs     = (int*)alloc((n + 1) * sizeof(int));
    int*   next     = (int*)alloc(n * sizeof(int));
    int*   bsum     = (int*)alloc(nb * sizeof(int));
    int*   boff     = (int*)alloc(nb * sizeof(int));
    int2*  sc       = (int2*)alloc((size_t)E * sizeof(int2));

    hipMemsetAsync(cnt_row, 0, n * sizeof(int), stream);
    hipMemsetAsync(cnt_col, 0, n * sizeof(int), stream);

    // 0) pack W -> bf16 transposed
    packw_kernel<<<64, 256, 0, stream>>>(weight, wbt);
    // 1) xw = x @ W (MFMA, bf16 output)
    xw_kernel<<<(n + 63) / 64, 256, 0, stream>>>(x, wbt, xwb, n);
    // 2) histograms
    hist_kernel<<<2048, 256, 0, stream>>>(ei, cnt_row, cnt_col, E);
    // 3) blocksum + dinv + combo
    blocksum_kernel<<<nb, 256, 0, stream>>>(cnt_col, cnt_row, dinv, bsum,
                                            emb0, emb1, emb2, combo, n);
    // 4) scan
    bscan_kernel<<<1, 256, 0, stream>>>(bsum, boff, nb, offs, n);
    offs_kernel<<<nb, 256, 0, stream>>>(cnt_col, boff, offs, next, n);
    // 5) fill CSR records
    fill_kernel<<<2048, 256, 0, stream>>>(ei, ef, dinv, next, sc, E);
    // 6) gather
    gather_kernel<<<(n + 3) / 4, 256, 0, stream>>>(xwb, sc, offs, dinv, combo, out, n);
}